// Round 1
// baseline (1218.052 us; speedup 1.0000x reference)
//
#include <hip/hip_runtime.h>
#include <hip/hip_bf16.h>
#include <cstdint>

#define B_ 256
#define D_ 128
#define T_ 512
#define H_ 256
#define C_ 10

#define SENT 0xFFFFFFFFFFFFFFFFull

using f32x4 = __attribute__((ext_vector_type(4))) float;
using s16x8 = __attribute__((ext_vector_type(8))) short;

__device__ __forceinline__ unsigned short f2bf(float f) {
    union { float f; uint32_t u; } a; a.f = f;
    uint32_t u = a.u;
    uint32_t r = (u + 0x7fffu + ((u >> 16) & 1u)) >> 16;   // RNE
    return (unsigned short)r;
}

__device__ __forceinline__ float sigm(float v) { return 1.0f / (1.0f + __expf(-v)); }

// ---------------------------------------------------------------------------
// Kernel 1: transpose x [B][D][T] f32  ->  xt [T][B][D] bf16
// ---------------------------------------------------------------------------
__global__ void xt_kernel(const float* __restrict__ x, unsigned short* __restrict__ xt) {
    __shared__ unsigned short tile[128][66];
    const int b  = blockIdx.x >> 3;
    const int t0 = (blockIdx.x & 7) << 6;
    const int tid = threadIdx.x;
    const int j  = tid & 63;
    const int dq = tid >> 6;

#pragma unroll
    for (int it = 0; it < 32; ++it) {
        int d = it * 4 + dq;
        tile[d][j] = f2bf(x[(size_t)(b * D_ + d) * T_ + t0 + j]);
    }
    __syncthreads();

    uint32_t* xt32 = (uint32_t*)xt;
#pragma unroll
    for (int it = 0; it < 16; ++it) {
        int tl = it * 4 + dq;
        int dp = j;
        uint32_t lo = tile[2 * dp][tl];
        uint32_t hi = tile[2 * dp + 1][tl];
        xt32[(size_t)((t0 + tl) * B_ + b) * (D_ / 2) + dp] = lo | (hi << 16);
    }
}

// ---------------------------------------------------------------------------
// Kernel 2: persistent LSTM recurrence.
// 256 blocks = 16 batch-chunks (bc) x 16 H-slices (hc), 256 threads (4 waves).
// Wave w = gate w. Per step: [16 x 384] @ [384 x 64] via mfma_16x16x32_bf16.
// h exchange: per-step slot in MALL-resident hbuf (T_ slots, 64 MB), data
// words are SELF-VALIDATING: buffer pre-set to 0xFF (bf16 NaN sentinel,
// unreachable for tanh*sigmoid outputs). Producers fire-and-forget relaxed
// u64 stores; consumers poll the data words directly. No flags, no vmcnt
// drain, no flag round trip: exactly ONE MALL traversal per step.
// Weight MFMA fragments are loop-invariant -> hoisted to registers (halves
// per-step LDS traffic).
// ---------------------------------------------------------------------------
__global__ void __launch_bounds__(256) lstm_kernel(
    const float* __restrict__ Wgx, const float* __restrict__ Wix,
    const float* __restrict__ Wfx, const float* __restrict__ Wox,
    const float* __restrict__ Wgh, const float* __restrict__ Wih,
    const float* __restrict__ Wfh, const float* __restrict__ Woh,
    const float* __restrict__ bg,  const float* __restrict__ bi,
    const float* __restrict__ bf2, const float* __restrict__ bo,
    const unsigned short* __restrict__ xt,
    uint64_t* __restrict__ hbuf,
    float* __restrict__ hfin)
{
    __shared__ __align__(16) unsigned short Wh_s[4][16][264];
    __shared__ __align__(16) unsigned short Wx_s[4][16][136];
    __shared__ __align__(16) unsigned short h_s[16][264];
    __shared__ __align__(16) unsigned short x_s[16][136];
    __shared__ float pre_s[4][16][17];
    __shared__ float bias_s[4][16];

    const int tid  = threadIdx.x;
    const int bc   = blockIdx.x & 15;
    const int hc   = blockIdx.x >> 4;
    const int wave = tid >> 6;
    const int lane = tid & 63;
    const int mrow = lane & 15;
    const int quad = lane >> 4;

    const float* Wh[4] = {Wgh, Wih, Wfh, Woh};
    const float* Wx[4] = {Wgx, Wix, Wfx, Wox};
    const float* bias[4] = {bg, bi, bf2, bo};

#pragma unroll
    for (int g = 0; g < 4; ++g) {
        for (int it = 0; it < 16; ++it) {
            int idx = it * 256 + tid;
            int k = idx >> 4, c = idx & 15;
            Wh_s[g][c][k] = f2bf(Wh[g][(size_t)k * H_ + hc * 16 + c]);
        }
        for (int it = 0; it < 8; ++it) {
            int idx = it * 256 + tid;
            int k = idx >> 4, c = idx & 15;
            Wx_s[g][c][k] = f2bf(Wx[g][(size_t)k * H_ + hc * 16 + c]);
        }
    }
    if (tid < 64) bias_s[tid >> 4][tid & 15] = bias[tid >> 4][hc * 16 + (tid & 15)];
    __syncthreads();

    // Hoist this wave's weight fragments (loop-invariant B operands) to regs.
    s16x8 wxf[4], whf[8];
#pragma unroll
    for (int kk = 0; kk < 4; ++kk)
        wxf[kk] = *(const s16x8*)&Wx_s[wave][mrow][kk * 32 + quad * 8];
#pragma unroll
    for (int kk = 0; kk < 8; ++kk)
        whf[kk] = *(const s16x8*)&Wh_s[wave][mrow][kk * 32 + quad * 8];

    const int b_l = tid >> 4;
    const int u_l = tid & 15;
    float c_st = 0.0f, h_st = 0.0f;

    // per-thread h-exchange coords: i=0..3 -> row = i*4+wave (0..15), col = lane
    uint64_t hv[4] = {SENT, SENT, SENT, SENT};

    // prefetch x for t=0
    uint4 xv = *(const uint4*)(xt + ((size_t)(0 * B_ + bc * 16 + b_l) * D_ + u_l * 8));

    for (int t = 0; t < T_; ++t) {
        // publish this step's x into LDS (xv prefetched last iteration)
        *(uint4*)&x_s[b_l][u_l * 8] = xv;
        __syncthreads();   // A: x_s visible

        // prefetch next step's x (arrives long before it's needed)
        if (t + 1 < T_)
            xv = *(const uint4*)(xt + ((size_t)((t + 1) * B_ + bc * 16 + b_l) * D_ + u_l * 8));

        // x-part MFMAs overlap with the in-flight h[t-1] poll loads
        f32x4 accx = {0.f, 0.f, 0.f, 0.f};
#pragma unroll
        for (int kk = 0; kk < 4; ++kk) {
            s16x8 a = *(const s16x8*)&x_s[mrow][kk * 32 + quad * 8];
            accx = __builtin_amdgcn_mfma_f32_16x16x32_bf16(a, wxf[kk], accx, 0, 0, 0);
        }

        if (t > 0) {
            // complete the h[t-1] loads issued at the end of last iteration;
            // retry (batched) any word still holding the sentinel.
            const uint64_t* src = hbuf + (size_t)(t - 1) * (B_ * (H_ / 4));
            for (;;) {
                bool ok = true;
#pragma unroll
                for (int i = 0; i < 4; ++i) ok &= (hv[i] != SENT);
                if (ok) break;
                __builtin_amdgcn_s_sleep(1);
#pragma unroll
                for (int i = 0; i < 4; ++i)
                    if (hv[i] == SENT)
                        hv[i] = __hip_atomic_load(
                            &src[(size_t)(bc * 16 + i * 4 + wave) * (H_ / 4) + lane],
                            __ATOMIC_RELAXED, __HIP_MEMORY_SCOPE_AGENT);
            }
#pragma unroll
            for (int i = 0; i < 4; ++i)
                *(uint64_t*)&h_s[i * 4 + wave][lane * 4] = hv[i];
        }
        __syncthreads();   // B: h_s ready

        f32x4 acc0 = {0.f, 0.f, 0.f, 0.f};
        f32x4 acc1 = {0.f, 0.f, 0.f, 0.f};
        if (t > 0) {
#pragma unroll
            for (int j = 0; j < 4; ++j) {
                s16x8 a  = *(const s16x8*)&h_s[mrow][(2 * j) * 32 + quad * 8];
                acc0 = __builtin_amdgcn_mfma_f32_16x16x32_bf16(a, whf[2 * j], acc0, 0, 0, 0);
                s16x8 a2 = *(const s16x8*)&h_s[mrow][(2 * j + 1) * 32 + quad * 8];
                acc1 = __builtin_amdgcn_mfma_f32_16x16x32_bf16(a2, whf[2 * j + 1], acc1, 0, 0, 0);
            }
        }

#pragma unroll
        for (int r = 0; r < 4; ++r)
            pre_s[wave][quad * 4 + r][mrow] = accx[r] + acc0[r] + acc1[r];
        __syncthreads();   // C: pre-activations ready

        float pg = pre_s[0][b_l][u_l] + bias_s[0][u_l];
        float pi = pre_s[1][b_l][u_l] + bias_s[1][u_l];
        float pf = pre_s[2][b_l][u_l] + bias_s[2][u_l];
        float po = pre_s[3][b_l][u_l] + bias_s[3][u_l];
        float gg = 2.0f * sigm(2.0f * pg) - 1.0f;   // tanh
        float ii = sigm(pi), ff = sigm(pf), oo = sigm(po);
        c_st = gg * ii + c_st * ff;
        float th = 2.0f * sigm(2.0f * c_st) - 1.0f; // tanh(c)
        h_st = th * oo;

        // pack 4 units into a u64 and publish (fire-and-forget, self-validating)
        uint32_t hb = f2bf(h_st);
        uint32_t p = hb | ((uint32_t)__shfl_down((int)hb, 1, 64) << 16);
        uint32_t q = (uint32_t)__shfl_down((int)p, 2, 64);
        if ((tid & 3) == 0) {
            uint64_t val = ((uint64_t)q << 32) | (uint64_t)p;
            uint64_t* dst = hbuf + (size_t)t * (B_ * (H_ / 4));
            __hip_atomic_store(&dst[(size_t)(bc * 16 + b_l) * (H_ / 4) + hc * 4 + (u_l >> 2)],
                               val, __ATOMIC_RELAXED, __HIP_MEMORY_SCOPE_AGENT);
        }

        // early-issue next step's h loads; stragglers resolved by retry above
        if (t + 1 < T_) {
            const uint64_t* src = hbuf + (size_t)t * (B_ * (H_ / 4));
#pragma unroll
            for (int i = 0; i < 4; ++i)
                hv[i] = __hip_atomic_load(
                    &src[(size_t)(bc * 16 + i * 4 + wave) * (H_ / 4) + lane],
                    __ATOMIC_RELAXED, __HIP_MEMORY_SCOPE_AGENT);
        }
    }

    hfin[(size_t)(bc * 16 + b_l) * H_ + hc * 16 + u_l] = h_st;
}

// ---------------------------------------------------------------------------
// Kernel 3: out = h_final @ W_ph + b_p
// ---------------------------------------------------------------------------
__global__ void proj_kernel(const float* __restrict__ hfin, const float* __restrict__ Wph,
                            const float* __restrict__ bp, float* __restrict__ out) {
    int gid = blockIdx.x * 256 + threadIdx.x;
    if (gid >= B_ * C_) return;
    int b = gid / C_, cc = gid % C_;
    float acc = bp[cc];
#pragma unroll 8
    for (int u = 0; u < H_; ++u)
        acc += hfin[(size_t)b * H_ + u] * Wph[(size_t)u * C_ + cc];
    out[gid] = acc;
}

// ---------------------------------------------------------------------------
extern "C" void kernel_launch(void* const* d_in, const int* in_sizes, int n_in,
                              void* d_out, int out_size, void* d_ws, size_t ws_size,
                              hipStream_t stream) {
    const float* x   = (const float*)d_in[0];
    const float* Wgx = (const float*)d_in[1];
    const float* Wix = (const float*)d_in[2];
    const float* Wfx = (const float*)d_in[3];
    const float* Wox = (const float*)d_in[4];
    const float* Wgh = (const float*)d_in[5];
    const float* Wih = (const float*)d_in[6];
    const float* Wfh = (const float*)d_in[7];
    const float* Woh = (const float*)d_in[8];
    const float* bg  = (const float*)d_in[9];
    const float* bi  = (const float*)d_in[10];
    const float* bf2 = (const float*)d_in[11];
    const float* bo  = (const float*)d_in[12];
    const float* Wph = (const float*)d_in[13];
    const float* bp  = (const float*)d_in[14];

    const size_t hbuf_bytes = (size_t)T_ * B_ * (H_ / 4) * sizeof(uint64_t); // 64 MB

    char* ws = (char*)d_ws;
    uint64_t*       hbuf = (uint64_t*)ws;
    float*          hfin = (float*)(ws + hbuf_bytes);
    unsigned short* xt   = (unsigned short*)(ws + hbuf_bytes + (size_t)B_ * H_ * sizeof(float));

    // sentinel-fill the h exchange buffer (bf16 NaN pattern 0xFFFF)
    hipMemsetAsync(hbuf, 0xFF, hbuf_bytes, stream);

    xt_kernel<<<B_ * (T_ / 64), 256, 0, stream>>>(x, xt);

    lstm_kernel<<<256, 256, 0, stream>>>(Wgx, Wix, Wfx, Wox, Wgh, Wih, Wfh, Woh,
                                         bg, bi, bf2, bo, xt, hbuf, hfin);

    proj_kernel<<<(B_ * C_ + 255) / 256, 256, 0, stream>>>(hfin, Wph, bp, (float*)d_out);
}